// Round 15
// baseline (4924.417 us; speedup 1.0000x reference)
//
#include <hip/hip_runtime.h>
#include <math.h>

#define B_SZ 32
#define T_SZ 2048
#define DIN 256
#define DH 256
#define FOUR_D 1024

// scan decomposition: 8 WGs per batch, 512 threads each (R9 skeleton)
#define NW 8
#define DPW 32
#define COLS 128       // preact cols per WG (4 gates x 32 dims)
#define KSEG 4         // 512 threads = 128 cols x 4 K-segments
#define KLEN 64        // K elements per segment -> 8 f16 chunks of 8

typedef _Float16 f16x2 __attribute__((ext_vector_type(2)));

#if __has_builtin(__builtin_amdgcn_fdot2)
#define FDOT2(a, b, c) __builtin_amdgcn_fdot2((a), (b), (c), false)
#else
__device__ __forceinline__ float fdot2_emu(f16x2 a, f16x2 b, float c) {
    return c + (float)a[0] * (float)b[0] + (float)a[1] * (float)b[1];
}
#define FDOT2(a, b, c) fdot2_emu((a), (b), (c))
#endif

__global__ void zero_ws(unsigned int* p, int n) {
    int i = blockIdx.x * blockDim.x + threadIdx.x;
    if (i < n) p[i] = 0u;
}

// px[r][f] = bias[f] + sum_k x_row(r)[k] * W[k][f];  r = tt*32 + b   (proven)
__global__ __launch_bounds__(256) void px_gemm(
    const float* __restrict__ x, const float* __restrict__ W,
    const float* __restrict__ bias, float* __restrict__ px,
    int t0)
{
    __shared__ float xt[16][DIN];
    const int tid = threadIdx.x;
    const int rbase = blockIdx.x * 16;

    {
        int row = tid >> 4;
        int seg = (tid & 15) * 16;
        int r = rbase + row;
        int bb = r & 31;
        int tt = r >> 5;
        const float4* s4 = (const float4*)(x + ((size_t)bb * T_SZ + (size_t)(t0 + tt)) * DIN + seg);
        float4* dst = (float4*)&xt[row][seg];
        dst[0] = s4[0]; dst[1] = s4[1]; dst[2] = s4[2]; dst[3] = s4[3];
    }
    __syncthreads();

    const int j = tid * 4;
    float4 bv = *(const float4*)&bias[j];
    float acc[16][4];
#pragma unroll
    for (int r = 0; r < 16; ++r) {
        acc[r][0] = bv.x; acc[r][1] = bv.y; acc[r][2] = bv.z; acc[r][3] = bv.w;
    }

    for (int k = 0; k < DIN; k += 4) {
        float4 w0 = *(const float4*)&W[(size_t)(k + 0) * FOUR_D + j];
        float4 w1 = *(const float4*)&W[(size_t)(k + 1) * FOUR_D + j];
        float4 w2 = *(const float4*)&W[(size_t)(k + 2) * FOUR_D + j];
        float4 w3 = *(const float4*)&W[(size_t)(k + 3) * FOUR_D + j];
#pragma unroll
        for (int r = 0; r < 16; ++r) {
            float4 xv = *(const float4*)&xt[r][k];
            acc[r][0] += xv.x * w0.x + xv.y * w1.x + xv.z * w2.x + xv.w * w3.x;
            acc[r][1] += xv.x * w0.y + xv.y * w1.y + xv.z * w2.y + xv.w * w3.y;
            acc[r][2] += xv.x * w0.z + xv.y * w1.z + xv.z * w2.z + xv.w * w3.z;
            acc[r][3] += xv.x * w0.w + xv.y * w1.w + xv.z * w2.w + xv.w * w3.w;
        }
    }

#pragma unroll
    for (int r = 0; r < 16; ++r) {
        float4 st = make_float4(acc[r][0], acc[r][1], acc[r][2], acc[r][3]);
        *(float4*)&px[((size_t)(rbase + r)) * FOUR_D + j] = st;
    }
}

// L1-bypassing 8B load: served by the local XCD L2 where same-XCD plain
// stores land. Used only after a one-shot probe proves visibility (R11).
__device__ __forceinline__ unsigned long long load_sc0_u64(const unsigned long long* p) {
    unsigned long long r;
    asm volatile("global_load_dwordx2 %0, %1, off sc0\n\t"
                 "s_waitcnt vmcnt(0)"
                 : "=v"(r) : "v"(p) : "memory");
    return r;
}

// Transposed scan = R14 compute (LDS-resident f16 U + fdot2, no L2 U
// traffic) + R11 transport (XCD-affine L2 fast path with one-shot probe
// and permanent demotion; proven LLC path as fallback and first-touch).
__global__ __launch_bounds__(512, 2) void lstm_scan13(
    const float* __restrict__ px, const float* __restrict__ U,
    float* __restrict__ out,
    unsigned long long* __restrict__ hslow,
    unsigned long long* __restrict__ hfast,
    float* __restrict__ cstate, int t0, int ct)
{
    __shared__ _Float16 u_lds[COLS][256];   // 64 KB f16 U-slice
    __shared__ _Float16 h1_lds[DH];         // f16 h (poller-converted)
    __shared__ float red[KSEG][COLS + 1];
    __shared__ float act_s[COLS];

    // XCD-affine mapping (R11): blockIdx = 8j + x -> all 8 WGs of a batch
    // share XCD x under round-robin dispatch (heuristic only; correctness
    // is guaranteed by the probe/demotion protocol).
    const int xh = blockIdx.x & 7;
    const int j = blockIdx.x >> 3;
    const int b = xh * 4 + (j >> 3);   // batch
    const int w = j & 7;               // WG-within-batch
    const int tid = threadIdx.x;
    const int c = tid & (COLS - 1);    // col within WG: 0..127
    const int seg = tid >> 7;          // 0..3
    const int kbase = seg << 6;        // 0,64,128,192
    const int cx = c & 7;              // swizzle key
    const int gg = c >> 5, jj = c & 31;
    const int colg = (gg << 8) + (w << 5) + jj;   // global preact column

    // ---- prologue: stage U-slice to LDS as f16, chunk-swizzled (R14)
#pragma unroll 4
    for (int it = 0; it < 64; ++it) {
        int lin = (it << 9) + tid;
        int k = lin >> 7;               // 0..255
        int cidx = lin & 127;
        int gcol = ((cidx >> 5) << 8) + (w << 5) + (cidx & 31);
        float v = U[(size_t)k * FOUR_D + gcol];
        int m = k >> 3, je = k & 7;     // logical chunk 0..31, elem
        int phys = (m & 24) | ((m & 7) ^ (cidx & 7));
        u_lds[cidx][(phys << 3) + je] = (_Float16)v;
    }

    float c_reg = 0.0f;
    if (tid < DPW) c_reg = cstate[b * DH + (w << 5) + tid];
    __syncthreads();   // u_lds ready

    bool probed = false, fastok = false;

    for (int tt = 0; tt < ct; ++tt) {
        const int s = t0 + tt + 1;     // computing h_s from h_{s-1}

        // px prefetch (independent of h): issue before the spin
        float pxv = 0.0f;
        if (tid < COLS)
            pxv = px[((size_t)tt * B_SZ + b) * FOUR_D + colg];

        // acquire h_{s-1}: threads 0..255 poll their own dim (tag==step)
        if (tid < DH) {
            if (s == 1) {
                h1_lds[tid] = (_Float16)0.0f;
            } else {
                const unsigned want = (unsigned)(s - 1);
                const size_t off = ((size_t)((s - 1) & 1) * B_SZ + b) * DH + tid;
                unsigned long long v;
                if (!probed) {
                    do {
                        v = __hip_atomic_load(hslow + off, __ATOMIC_RELAXED,
                                              __HIP_MEMORY_SCOPE_AGENT);
                    } while ((unsigned)(v >> 32) != want);
                    unsigned long long f = load_sc0_u64(hfast + off);
                    fastok = ((unsigned)(f >> 32) == want);
                    probed = true;
                } else if (fastok) {
                    int tries = 0;
                    for (;;) {
                        v = load_sc0_u64(hfast + off);
                        if ((unsigned)(v >> 32) == want) break;
                        if (++tries > 1024) {      // permanent demotion
                            fastok = false;
                            do {
                                v = __hip_atomic_load(hslow + off, __ATOMIC_RELAXED,
                                                      __HIP_MEMORY_SCOPE_AGENT);
                            } while ((unsigned)(v >> 32) != want);
                            break;
                        }
                    }
                } else {
                    do {
                        v = __hip_atomic_load(hslow + off, __ATOMIC_RELAXED,
                                              __HIP_MEMORY_SCOPE_AGENT);
                    } while ((unsigned)(v >> 32) != want);
                }
                h1_lds[tid] = (_Float16)__uint_as_float((unsigned)v);
            }
        }
        __syncthreads();   // B1: h1_lds ready

        // GEMV: 8 chunks x { 1 swizzled b128 U read + 1 b128 h read
        // (wave-uniform broadcast) + 4 fdot2 }  (R14)
        float a0 = 0.f, a1 = 0.f, a2 = 0.f, a3 = 0.f;
#pragma unroll
        for (int t = 0; t < 8; ++t) {
            const f16x2* q = (const f16x2*)&u_lds[c][((seg << 3) + (t ^ cx)) << 3];
            const f16x2* hp = (const f16x2*)&h1_lds[kbase + (t << 3)];
            a0 = FDOT2(q[0], hp[0], a0);
            a1 = FDOT2(q[1], hp[1], a1);
            a2 = FDOT2(q[2], hp[2], a2);
            a3 = FDOT2(q[3], hp[3], a3);
        }
        red[seg][c] = (a0 + a1) + (a2 + a3);
        __syncthreads();   // B2: partials ready

        if (tid < COLS) {
            float pre = pxv + red[0][tid] + red[1][tid]
                            + red[2][tid] + red[3][tid];
            float a;
            if (tid < 96) {
                a = 1.0f / (1.0f + __expf(-pre));          // i, f, o
            } else {
                float e = __expf(-2.0f * pre);             // g = tanh
                a = 2.0f / (1.0f + e) - 1.0f;
            }
            act_s[tid] = a;
        }
        __syncthreads();   // B3: activations ready

        if (tid < DPW) {
            float ig = act_s[tid];
            float fg = act_s[32 + tid];
            float og = act_s[64 + tid];
            float gv = act_s[96 + tid];
            float cn = fg * c_reg + ig * gv;
            c_reg = cn;
            float ec = __expf(-2.0f * cn);
            float hn = og * (2.0f / (1.0f + ec) - 1.0f);
            const int d = (w << 5) + tid;
            unsigned long long pv =
                ((unsigned long long)(unsigned)s << 32) |
                (unsigned long long)__float_as_uint(hn);
            const size_t poff = ((size_t)(s & 1) * B_SZ + b) * DH + d;
            // fast transport first (local L2), then the proven LLC publish
            *(volatile unsigned long long*)(hfast + poff) = pv;
            __hip_atomic_store(hslow + poff, pv, __ATOMIC_RELAXED,
                               __HIP_MEMORY_SCOPE_AGENT);
            out[((size_t)b * T_SZ + (size_t)(s - 1)) * DH + d] = hn;
        }
        // no trailing barrier: h1_lds rewrite (pollers, pre-B1 of t+1) occurs
        // after B3_t, and all h1_lds readers finished before B2_t; red rewrite
        // gated behind B1_{t+1}; act_s behind B2_{t+1}. (R9 argument.)
    }

    if (tid < DPW) cstate[b * DH + (w << 5) + tid] = c_reg;
}

extern "C" void kernel_launch(void* const* d_in, const int* in_sizes, int n_in,
                              void* d_out, int out_size, void* d_ws, size_t ws_size,
                              hipStream_t stream) {
    const float* x    = (const float*)d_in[0];
    const float* W    = (const float*)d_in[1];
    const float* U    = (const float*)d_in[2];
    const float* bias = (const float*)d_in[3];
    float* out = (float*)d_out;

    // ws layout: cstate 32KB @0 | hslow 128KB @32K | hfast 128KB @160K | px @288K
    float* cstate = (float*)d_ws;
    unsigned long long* hslow = (unsigned long long*)((char*)d_ws + 32 * 1024);
    unsigned long long* hfast = (unsigned long long*)((char*)d_ws + 160 * 1024);
    size_t px_off = 288 * 1024;
    float* pxbuf = (float*)((char*)d_ws + px_off);

    size_t avail = (ws_size > px_off) ? (ws_size - px_off) : 0;
    size_t per_step = (size_t)B_SZ * FOUR_D * sizeof(float);  // 128 KB
    long ct_max = (long)(avail / per_step);
    int CT = (ct_max >= T_SZ) ? T_SZ : (int)ct_max;
    if (CT < 1) CT = 1;

    // zero cstate + hslow + hfast each launch
    int zero_words = (288 * 1024) / 4;
    zero_ws<<<(zero_words + 255) / 256, 256, 0, stream>>>((unsigned int*)d_ws, zero_words);

    for (int t0 = 0; t0 < T_SZ; t0 += CT) {
        int ct = (T_SZ - t0 < CT) ? (T_SZ - t0) : CT;
        int rows = ct * B_SZ;
        px_gemm<<<rows / 16, 256, 0, stream>>>(x, W, bias, pxbuf, t0);
        lstm_scan13<<<B_SZ * NW, 512, 0, stream>>>(
            pxbuf, U, out, hslow, hfast, cstate, t0, ct);
    }
}

// Round 16
// 3705.342 us; speedup vs baseline: 1.3290x; 1.3290x over previous
//
#include <hip/hip_runtime.h>
#include <math.h>

#define B_SZ 32
#define T_SZ 2048
#define DIN 256
#define DH 256
#define FOUR_D 1024

// scan decomposition: 8 WGs per batch, 512 threads each (R9 skeleton),
// wave-local tail: tid -> (dd = tid>>4, gate = (tid>>2)&3, seg = tid&3)
#define NW 8
#define DPW 32

// padded h index: stride-68 per 64-k block -> kbase banks 0,4,8,12 (no conflict)
#define IK(k) ((k) + ((k) >> 6) * 4)

__global__ void zero_ws(unsigned int* p, int n) {
    int i = blockIdx.x * blockDim.x + threadIdx.x;
    if (i < n) p[i] = 0u;
}

// px[r][f] = bias[f] + sum_k x_row(r)[k] * W[k][f];  r = tt*32 + b   (proven)
__global__ __launch_bounds__(256) void px_gemm(
    const float* __restrict__ x, const float* __restrict__ W,
    const float* __restrict__ bias, float* __restrict__ px,
    int t0)
{
    __shared__ float xt[16][DIN];
    const int tid = threadIdx.x;
    const int rbase = blockIdx.x * 16;

    {
        int row = tid >> 4;
        int seg = (tid & 15) * 16;
        int r = rbase + row;
        int bb = r & 31;
        int tt = r >> 5;
        const float4* s4 = (const float4*)(x + ((size_t)bb * T_SZ + (size_t)(t0 + tt)) * DIN + seg);
        float4* dst = (float4*)&xt[row][seg];
        dst[0] = s4[0]; dst[1] = s4[1]; dst[2] = s4[2]; dst[3] = s4[3];
    }
    __syncthreads();

    const int j = tid * 4;
    float4 bv = *(const float4*)&bias[j];
    float acc[16][4];
#pragma unroll
    for (int r = 0; r < 16; ++r) {
        acc[r][0] = bv.x; acc[r][1] = bv.y; acc[r][2] = bv.z; acc[r][3] = bv.w;
    }

    for (int k = 0; k < DIN; k += 4) {
        float4 w0 = *(const float4*)&W[(size_t)(k + 0) * FOUR_D + j];
        float4 w1 = *(const float4*)&W[(size_t)(k + 1) * FOUR_D + j];
        float4 w2 = *(const float4*)&W[(size_t)(k + 2) * FOUR_D + j];
        float4 w3 = *(const float4*)&W[(size_t)(k + 3) * FOUR_D + j];
#pragma unroll
        for (int r = 0; r < 16; ++r) {
            float4 xv = *(const float4*)&xt[r][k];
            acc[r][0] += xv.x * w0.x + xv.y * w1.x + xv.z * w2.x + xv.w * w3.x;
            acc[r][1] += xv.x * w0.y + xv.y * w1.y + xv.z * w2.y + xv.w * w3.y;
            acc[r][2] += xv.x * w0.z + xv.y * w1.z + xv.z * w2.z + xv.w * w3.z;
            acc[r][3] += xv.x * w0.w + xv.y * w1.w + xv.z * w2.w + xv.w * w3.w;
        }
    }

#pragma unroll
    for (int r = 0; r < 16; ++r) {
        float4 st = make_float4(acc[r][0], acc[r][1], acc[r][2], acc[r][3]);
        *(float4*)&px[((size_t)(rbase + r)) * FOUR_D + j] = st;
    }
}

// 16 named float4 weight registers (R9-proven; compiler remat from L2-hot U
// is accepted — issued post-B1 with 8-wave overlap).
#define REP16(M) M(0) M(1) M(2) M(3) M(4) M(5) M(6) M(7) \
                 M(8) M(9) M(10) M(11) M(12) M(13) M(14) M(15)

#define U_DECL(n) float4 u##n;
#define U_LOAD(n) u##n = make_float4(                         \
    Ucol[(size_t)(kbase + 4*(n) + 0) * FOUR_D],               \
    Ucol[(size_t)(kbase + 4*(n) + 1) * FOUR_D],               \
    Ucol[(size_t)(kbase + 4*(n) + 2) * FOUR_D],               \
    Ucol[(size_t)(kbase + 4*(n) + 3) * FOUR_D]);
#define GEMV_STEP(n) {                                        \
    float4 hv = *(const float4*)&hrow[4*(n)];                 \
    a0 += hv.x * u##n.x; a1 += hv.y * u##n.y;                 \
    a2 += hv.z * u##n.z; a3 += hv.w * u##n.w; }

// Transposed scan, single-barrier edition. Thread (dd,gate,seg) computes the
// seg-partial of preact column (gate,dd). Seg-reduce = 2 shfl_xor (lanes ±1,
// ±2); activation per-lane; gate-gather = 3 shfl (lanes ±4,8,12 — same wave);
// all 16 lanes of a dim compute the cell redundantly; lane (tid&15)==0
// publishes. h_lds parity-double-buffered + stride-padded. h exchange:
// proven agent-scope 64-bit tagged atomics.
__global__ __launch_bounds__(512, 2) void lstm_scan14(
    const float* __restrict__ px, const float* __restrict__ U,
    float* __restrict__ out, unsigned long long* __restrict__ hbuf,
    float* __restrict__ cstate, int t0, int ct)
{
    __shared__ float h_lds[2][272];    // padded: IK(255)=267

    const int b = blockIdx.x >> 3;     // batch (batch-contiguous)
    const int w = blockIdx.x & 7;      // WG-within-batch
    const int tid = threadIdx.x;
    const int dd = tid >> 4;           // dim within WG: 0..31
    const int gate = (tid >> 2) & 3;   // 0..3
    const int seg = tid & 3;           // K-segment: 0..3
    const int kbase = seg << 6;        // 0,64,128,192
    const int colg = (gate << 8) + (w << 5) + dd;   // global preact column
    const int d = (w << 5) + dd;       // global dim of this 16-lane group
    const bool pub = (tid & 15) == 0;  // publisher lane for dim d
    const float* Ucol = U + colg;

    float c_reg = cstate[b * DH + d];  // all 16 lanes hold the same value

    for (int tt = 0; tt < ct; ++tt) {
        const int s = t0 + tt + 1;     // computing h_s from h_{s-1}

        // px prefetch (independent of h): issue before the spin
        float pxv = px[((size_t)tt * B_SZ + b) * FOUR_D + colg];

        // acquire h_{s-1} into h_lds[tt&1]. Local 32 dims are pre-written by
        // the publisher lanes (except at chunk start, where we poll/init all).
        if (tid < DH) {
            const bool local = (tid >> 5) == w;
            if (tt == 0 && t0 == 0) {
                h_lds[0][IK(tid)] = 0.0f;
            } else if (tt == 0 || !local) {
                const unsigned long long want = (unsigned long long)(unsigned)(s - 1);
                const unsigned long long* slot = hbuf +
                    (((size_t)((s - 1) & 1) * B_SZ + b) * DH + tid);
                unsigned long long v;
                do {
                    v = __hip_atomic_load(slot, __ATOMIC_RELAXED,
                                          __HIP_MEMORY_SCOPE_AGENT);
                } while ((v >> 32) != want);
                h_lds[tt & 1][IK(tid)] = __uint_as_float((unsigned)v);
            }
        }
        __syncthreads();   // B1 (the only barrier): h_lds[tt&1] complete

        // GEMV: 64 FMAs over this thread's K-segment, h from padded LDS
        const float* hrow = &h_lds[tt & 1][kbase + (seg << 2)];
        REP16(U_DECL)
        REP16(U_LOAD)
        float a0 = 0.f, a1 = 0.f, a2 = 0.f, a3 = 0.f;
        REP16(GEMV_STEP)
        float p = (a0 + a1) + (a2 + a3);

        // seg butterfly: all 4 lanes of (dd,gate) get the full dot
        p += __shfl_xor(p, 1);
        p += __shfl_xor(p, 2);
        float pre = pxv + p;

        // per-lane activation (gate 3 = tanh, else sigmoid)
        float act;
        if (gate < 3) {
            act = 1.0f / (1.0f + __expf(-pre));
        } else {
            float e = __expf(-2.0f * pre);
            act = 2.0f / (1.0f + e) - 1.0f;
        }

        // gate gather within the wave: base lane = (dim group)| seg
        const int bl = (tid & 48) | seg;
        float ig = __shfl(act, bl);
        float fg = __shfl(act, bl | 4);
        float og = __shfl(act, bl | 8);
        float gv = __shfl(act, bl | 12);

        // cell update (all 16 lanes of dim d compute identically)
        float cn = fg * c_reg + ig * gv;
        c_reg = cn;
        float ec = __expf(-2.0f * cn);
        float hn = og * (2.0f / (1.0f + ec) - 1.0f);

        if (pub) {
            // publish FIRST (critical path), then local h_lds, then out
            unsigned long long pv =
                ((unsigned long long)(unsigned)s << 32) |
                (unsigned long long)__float_as_uint(hn);
            __hip_atomic_store(hbuf + (((size_t)(s & 1) * B_SZ + b) * DH + d),
                               pv, __ATOMIC_RELAXED, __HIP_MEMORY_SCOPE_AGENT);
            h_lds[(tt + 1) & 1][IK(d)] = hn;   // local dim for next step
            out[((size_t)b * T_SZ + (size_t)(s - 1)) * DH + d] = hn;
        }
        // single-barrier safety: writers of slot (tt+1)&1 (publisher now,
        // pollers of iter tt+1) are separated from that slot's readers
        // (GEMV of iter tt+1) by B1_{tt+1}; readers of slot tt&1 (this
        // iter's GEMV) finished before any same-parity rewrite, which can
        // only happen at iter tt+2, gated by B1_{tt+2} > B1_{tt+1}.
    }

    if (pub) cstate[b * DH + d] = c_reg;
}

extern "C" void kernel_launch(void* const* d_in, const int* in_sizes, int n_in,
                              void* d_out, int out_size, void* d_ws, size_t ws_size,
                              hipStream_t stream) {
    const float* x    = (const float*)d_in[0];
    const float* W    = (const float*)d_in[1];
    const float* U    = (const float*)d_in[2];
    const float* bias = (const float*)d_in[3];
    float* out = (float*)d_out;

    // ws layout: cstate 32KB @0 | hbuf 128KB @32K | pxbuf @160K
    float* cstate = (float*)d_ws;
    unsigned long long* hbuf = (unsigned long long*)((char*)d_ws + 32 * 1024);
    size_t px_off = 160 * 1024;
    float* pxbuf = (float*)((char*)d_ws + px_off);

    size_t avail = (ws_size > px_off) ? (ws_size - px_off) : 0;
    size_t per_step = (size_t)B_SZ * FOUR_D * sizeof(float);  // 128 KB
    long ct_max = (long)(avail / per_step);
    int CT = (ct_max >= T_SZ) ? T_SZ : (int)ct_max;
    if (CT < 1) CT = 1;

    // zero cstate + hbuf each launch
    int zero_words = (160 * 1024) / 4;
    zero_ws<<<(zero_words + 255) / 256, 256, 0, stream>>>((unsigned int*)d_ws, zero_words);

    for (int t0 = 0; t0 < T_SZ; t0 += CT) {
        int ct = (T_SZ - t0 < CT) ? (T_SZ - t0) : CT;
        int rows = ct * B_SZ;
        px_gemm<<<rows / 16, 256, 0, stream>>>(x, W, bias, pxbuf, t0);
        lstm_scan14<<<B_SZ * NW, 512, 0, stream>>>(pxbuf, U, out, hbuf, cstate, t0, ct);
    }
}

// Round 17
// 3456.945 us; speedup vs baseline: 1.4245x; 1.0719x over previous
//
#include <hip/hip_runtime.h>
#include <math.h>

#define B_SZ 32
#define T_SZ 2048
#define DIN 256
#define DH 256
#define FOUR_D 1024

// scan: 8 WGs per batch, 512 threads (R16 skeleton)
// thread -> (dd = tid>>4, gate = (tid>>2)&3, seg = tid&3)
#define NW 8
#define DPW 32

// padded f16 h index: +8 f16 (16B) per 64-elem block
#define IK16(k) ((k) + ((k) >> 6) * 8)
// u_lds row stride in f16 elems (264*2=528B -> bank shift 4/row)
#define USTR 264

typedef _Float16 f16x2 __attribute__((ext_vector_type(2)));

#if __has_builtin(__builtin_amdgcn_fdot2)
#define FDOT2(a, b, c) __builtin_amdgcn_fdot2((a), (b), (c), false)
#else
__device__ __forceinline__ float fdot2_emu(f16x2 a, f16x2 b, float c) {
    return c + (float)a[0] * (float)b[0] + (float)a[1] * (float)b[1];
}
#define FDOT2(a, b, c) fdot2_emu((a), (b), (c))
#endif

__device__ __forceinline__ f16x2 H2(float f) {
    union { float f; f16x2 h; } u; u.f = f; return u.h;
}

__global__ void zero_ws(unsigned int* p, int n) {
    int i = blockIdx.x * blockDim.x + threadIdx.x;
    if (i < n) p[i] = 0u;
}

// px[r][f] = bias[f] + sum_k x_row(r)[k] * W[k][f];  r = tt*32 + b   (proven)
__global__ __launch_bounds__(256) void px_gemm(
    const float* __restrict__ x, const float* __restrict__ W,
    const float* __restrict__ bias, float* __restrict__ px,
    int t0)
{
    __shared__ float xt[16][DIN];
    const int tid = threadIdx.x;
    const int rbase = blockIdx.x * 16;

    {
        int row = tid >> 4;
        int seg = (tid & 15) * 16;
        int r = rbase + row;
        int bb = r & 31;
        int tt = r >> 5;
        const float4* s4 = (const float4*)(x + ((size_t)bb * T_SZ + (size_t)(t0 + tt)) * DIN + seg);
        float4* dst = (float4*)&xt[row][seg];
        dst[0] = s4[0]; dst[1] = s4[1]; dst[2] = s4[2]; dst[3] = s4[3];
    }
    __syncthreads();

    const int j = tid * 4;
    float4 bv = *(const float4*)&bias[j];
    float acc[16][4];
#pragma unroll
    for (int r = 0; r < 16; ++r) {
        acc[r][0] = bv.x; acc[r][1] = bv.y; acc[r][2] = bv.z; acc[r][3] = bv.w;
    }

    for (int k = 0; k < DIN; k += 4) {
        float4 w0 = *(const float4*)&W[(size_t)(k + 0) * FOUR_D + j];
        float4 w1 = *(const float4*)&W[(size_t)(k + 1) * FOUR_D + j];
        float4 w2 = *(const float4*)&W[(size_t)(k + 2) * FOUR_D + j];
        float4 w3 = *(const float4*)&W[(size_t)(k + 3) * FOUR_D + j];
#pragma unroll
        for (int r = 0; r < 16; ++r) {
            float4 xv = *(const float4*)&xt[r][k];
            acc[r][0] += xv.x * w0.x + xv.y * w1.x + xv.z * w2.x + xv.w * w3.x;
            acc[r][1] += xv.x * w0.y + xv.y * w1.y + xv.z * w2.y + xv.w * w3.y;
            acc[r][2] += xv.x * w0.z + xv.y * w1.z + xv.z * w2.z + xv.w * w3.z;
            acc[r][3] += xv.x * w0.w + xv.y * w1.w + xv.z * w2.w + xv.w * w3.w;
        }
    }

#pragma unroll
    for (int r = 0; r < 16; ++r) {
        float4 st = make_float4(acc[r][0], acc[r][1], acc[r][2], acc[r][3]);
        *(float4*)&px[((size_t)(rbase + r)) * FOUR_D + j] = st;
    }
}

// Single-barrier transposed scan (R16) + LDS-resident f16 U + fdot2.
// U layout: row = dd*4+gate (stride 264 f16); logical chunk (seg,c) stored at
// p = (c>>1)*8 + seg*2 + (c&1)  =>  start bank 4*((row+p)&7): per quarter-wave
// each bank-group hit exactly 2x (free, m136). U chunks pre-loaded to pinned
// regs once (worst case: cheap LDS re-read, never the 0.9us L2 re-stream).
__global__ __launch_bounds__(512, 2) void lstm_scan15(
    const float* __restrict__ px, const float* __restrict__ U,
    float* __restrict__ out, unsigned long long* __restrict__ hbuf,
    float* __restrict__ cstate, int t0, int ct)
{
    __shared__ _Float16 u_lds[128 * USTR];   // ~66 KB
    __shared__ _Float16 h1_lds[2][288];      // padded f16 h, parity dbuf

    const int b = blockIdx.x >> 3;     // batch (batch-contiguous)
    const int w = blockIdx.x & 7;      // WG-within-batch
    const int tid = threadIdx.x;
    const int dd = tid >> 4;           // dim within WG: 0..31
    const int gate = (tid >> 2) & 3;   // 0..3
    const int seg = tid & 3;           // K-segment: 0..3 (64 k each)
    const int colg = (gate << 8) + (w << 5) + dd;   // global preact column
    const int d = (w << 5) + dd;       // global dim of this 16-lane group
    const bool pub = (tid & 15) == 0;  // publisher lane for dim d

    // ---- prologue: stage U-slice to LDS as f16, conflict-free layout
    for (int it = 0; it < 64; ++it) {
        int lin = (it << 9) + tid;          // 0..32767
        int row = lin & 127;                // = dd*4 + gate
        int kk = lin >> 7;                  // 0..255
        int gcol = ((row & 3) << 8) + (w << 5) + (row >> 2);
        float v = U[(size_t)kk * FOUR_D + gcol];
        int sg = kk >> 6;                   // k-segment
        int cc = (kk >> 3) & 7;             // chunk within segment
        int jj = kk & 7;                    // elem within chunk
        int p = ((cc >> 1) << 3) + (sg << 1) + (cc & 1);
        u_lds[row * USTR + (p << 3) + jj] = (_Float16)v;
    }
    float c_reg = cstate[b * DH + d];
    __syncthreads();   // u_lds ready

    // ---- one-time: this thread's 8 U chunks -> pinned registers (from LDS)
    const int rowbase = (dd * 4 + gate) * USTR;
    float4 uq[8];
#pragma unroll
    for (int c2 = 0; c2 < 8; ++c2) {
        int p = ((c2 >> 1) << 3) + (seg << 1) + (c2 & 1);
        uq[c2] = *(const float4*)&u_lds[rowbase + (p << 3)];
    }
#pragma unroll
    for (int c2 = 0; c2 < 8; ++c2) {
        asm volatile("" : "+v"(uq[c2].x), "+v"(uq[c2].y),
                          "+v"(uq[c2].z), "+v"(uq[c2].w));
    }

    for (int tt = 0; tt < ct; ++tt) {
        const int s = t0 + tt + 1;     // computing h_s from h_{s-1}

        // px prefetch (independent of h): issue before the spin
        float pxv = px[((size_t)tt * B_SZ + b) * FOUR_D + colg];

        // acquire h_{s-1} into h1_lds[tt&1] (f16). Local dims pre-written by
        // publishers except at chunk start.
        if (tid < DH) {
            const bool local = (tid >> 5) == w;
            if (tt == 0 && t0 == 0) {
                h1_lds[0][IK16(tid)] = (_Float16)0.0f;
            } else if (tt == 0 || !local) {
                const unsigned long long want = (unsigned long long)(unsigned)(s - 1);
                const unsigned long long* slot = hbuf +
                    (((size_t)((s - 1) & 1) * B_SZ + b) * DH + tid);
                unsigned long long v;
                do {
                    v = __hip_atomic_load(slot, __ATOMIC_RELAXED,
                                          __HIP_MEMORY_SCOPE_AGENT);
                } while ((v >> 32) != want);
                h1_lds[tt & 1][IK16(tid)] = (_Float16)__uint_as_float((unsigned)v);
            }
        }
        __syncthreads();   // B1 (only barrier): h1_lds[tt&1] complete

        // GEMV: 8 chunks x { 1 padded b128 h read (broadcast) + 4 fdot2 },
        // U from pinned registers
        const _Float16* hrow = &h1_lds[tt & 1][seg * 72];
        float a0 = 0.f, a1 = 0.f, a2 = 0.f, a3 = 0.f;
#pragma unroll
        for (int c2 = 0; c2 < 8; ++c2) {
            float4 hv = *(const float4*)&hrow[c2 << 3];
            a0 = FDOT2(H2(uq[c2].x), H2(hv.x), a0);
            a1 = FDOT2(H2(uq[c2].y), H2(hv.y), a1);
            a2 = FDOT2(H2(uq[c2].z), H2(hv.z), a2);
            a3 = FDOT2(H2(uq[c2].w), H2(hv.w), a3);
        }
        float pr = (a0 + a1) + (a2 + a3);

        // seg butterfly: lanes ±1, ±2 (seg bits are tid[1:0])
        pr += __shfl_xor(pr, 1);
        pr += __shfl_xor(pr, 2);
        float pre = pxv + pr;

        // per-lane activation (gate 3 = tanh, else sigmoid)
        float act;
        if (gate < 3) {
            act = 1.0f / (1.0f + __expf(-pre));
        } else {
            float e = __expf(-2.0f * pre);
            act = 2.0f / (1.0f + e) - 1.0f;
        }

        // gate gather within the wave
        const int bl = (tid & 48) | seg;
        float ig = __shfl(act, bl);
        float fg = __shfl(act, bl | 4);
        float og = __shfl(act, bl | 8);
        float gv = __shfl(act, bl | 12);

        // cell update (16 lanes of dim d compute identically)
        float cn = fg * c_reg + ig * gv;
        c_reg = cn;
        float ec = __expf(-2.0f * cn);
        float hn = og * (2.0f / (1.0f + ec) - 1.0f);

        if (pub) {
            unsigned long long pv =
                ((unsigned long long)(unsigned)s << 32) |
                (unsigned long long)__float_as_uint(hn);
            __hip_atomic_store(hbuf + (((size_t)(s & 1) * B_SZ + b) * DH + d),
                               pv, __ATOMIC_RELAXED, __HIP_MEMORY_SCOPE_AGENT);
            h1_lds[(tt + 1) & 1][IK16(d)] = (_Float16)hn;   // local dim
            out[((size_t)b * T_SZ + (size_t)(s - 1)) * DH + d] = hn;
        }
        // single-barrier safety: same parity/rendezvous argument as R16.
    }

    if (pub) cstate[b * DH + d] = c_reg;
}

extern "C" void kernel_launch(void* const* d_in, const int* in_sizes, int n_in,
                              void* d_out, int out_size, void* d_ws, size_t ws_size,
                              hipStream_t stream) {
    const float* x    = (const float*)d_in[0];
    const float* W    = (const float*)d_in[1];
    const float* U    = (const float*)d_in[2];
    const float* bias = (const float*)d_in[3];
    float* out = (float*)d_out;

    // ws layout: cstate 32KB @0 | hbuf 128KB @32K | pxbuf @160K
    float* cstate = (float*)d_ws;
    unsigned long long* hbuf = (unsigned long long*)((char*)d_ws + 32 * 1024);
    size_t px_off = 160 * 1024;
    float* pxbuf = (float*)((char*)d_ws + px_off);

    size_t avail = (ws_size > px_off) ? (ws_size - px_off) : 0;
    size_t per_step = (size_t)B_SZ * FOUR_D * sizeof(float);  // 128 KB
    long ct_max = (long)(avail / per_step);
    int CT = (ct_max >= T_SZ) ? T_SZ : (int)ct_max;
    if (CT < 1) CT = 1;

    // zero cstate + hbuf each launch
    int zero_words = (160 * 1024) / 4;
    zero_ws<<<(zero_words + 255) / 256, 256, 0, stream>>>((unsigned int*)d_ws, zero_words);

    for (int t0 = 0; t0 < T_SZ; t0 += CT) {
        int ct = (T_SZ - t0 < CT) ? (T_SZ - t0) : CT;
        int rows = ct * B_SZ;
        px_gemm<<<rows / 16, 256, 0, stream>>>(x, W, bias, pxbuf, t0);
        lstm_scan15<<<B_SZ * NW, 512, 0, stream>>>(pxbuf, U, out, hbuf, cstate, t0, ct);
    }
}